// Round 14
// baseline (237.396 us; speedup 1.0000x reference)
//
#include <hip/hip_runtime.h>
#include <hip/hip_fp16.h>

// Problem constants: B=4, H=W=256, C=64, OC=64, K=3, PAD=1
#define FEAT_N (4*64*256*256)
#define OFFS_N (4*18*256*256)
#define WTF_N  (576*64)            // deform weights, fp16, MFMA-B-fragment order
#define WT2F_N (576*32)            // offset-conv weights, fp16 frags, N padded to 32
#define WT1F_N (4*64*8)            // conv1 weights, fp16 B-frags, K=32 (27 real), N=64

typedef __attribute__((ext_vector_type(8))) _Float16 half8;
typedef __attribute__((ext_vector_type(4))) float float4v;
typedef __attribute__((ext_vector_type(4))) unsigned uint4v;

__device__ __forceinline__ unsigned short f2h(float f) {
    union { __half h; unsigned short u; } c; c.h = __float2half_rn(f); return c.u;
}
__device__ __forceinline__ __half2 u2h2(unsigned u) {
    union { unsigned u; __half2 h; } c; c.u = u; return c.h;
}
__device__ __forceinline__ unsigned h22u(__half2 h) {
    union { __half2 h; unsigned u; } c; c.h = h; return c.u;
}

// ---------------------------------------------------------------------------
// Weight prep (EXACT R13): wtf, wt2f (oc>=18 zero), wt1f. All fp16.
// ---------------------------------------------------------------------------
__global__ __launch_bounds__(256) void prep_weights(const float* __restrict__ dw,
                                                    const float* __restrict__ ow,
                                                    const float* __restrict__ cw,
                                                    unsigned short* __restrict__ wtf,
                                                    unsigned short* __restrict__ wt2f,
                                                    unsigned short* __restrict__ wt1f) {
    int idx = blockIdx.x * 256 + threadIdx.x;
    if (idx < WTF_N) {
        int j    = idx & 7;
        int lane = (idx >> 3) & 63;
        int nt   = (idx >> 9) & 3;
        int ks   = idx >> 11;
        int k    = ks * 32 + ((lane >> 4) << 3) + j;
        int tap  = k >> 6;
        int ic   = k & 63;
        int n    = nt * 16 + (lane & 15);
        wtf[idx] = f2h(dw[n * 576 + ic * 9 + tap]);
    }
    int i2 = idx - WTF_N;
    if (i2 >= 0 && i2 < WT2F_N) {
        int j    = i2 & 7;
        int lane = (i2 >> 3) & 63;
        int nt   = (i2 >> 9) & 1;
        int ks   = i2 >> 10;
        int k    = ks * 32 + ((lane >> 4) << 3) + j;
        int tap  = k >> 6;
        int ic   = k & 63;
        int n    = nt * 16 + (lane & 15);
        wt2f[i2] = (n < 18) ? f2h(ow[n * 576 + ic * 9 + tap]) : (unsigned short)0;
    }
    int i3 = idx - WTF_N - WT2F_N;
    if (i3 >= 0 && i3 < WT1F_N) {
        int j    = i3 & 7;
        int lane = (i3 >> 3) & 63;
        int nt   = (i3 >> 9) & 3;
        int n    = nt * 16 + (lane & 15);
        int k    = ((lane >> 4) << 3) + j;
        wt1f[i3] = (k < 27) ? f2h(cw[n * 27 + k]) : (unsigned short)0;
    }
}

// ---------------------------------------------------------------------------
// conv1 (EXACT R13): MFMA im2col GEMM, M=256 px, N=64 oc, K=32, fp16.
// ---------------------------------------------------------------------------
__global__ __launch_bounds__(256) void conv1_kernel(const float* __restrict__ x,
                                                    const unsigned short* __restrict__ wt1f,
                                                    const float* __restrict__ cb,
                                                    unsigned short* __restrict__ featp) {
    __shared__ unsigned short xs[10 * 264];   // rows 0..8 = (ic*3+ti), row 9 = zeros
    const int tid  = threadIdx.x;
    const int lane = tid & 63;
    const int wave = tid >> 6;
    const int lm   = lane & 15;
    const int quad = lane >> 4;

    const int bx = blockIdx.x;
    const int b  = bx >> 8;
    const int h  = bx & 255;

#pragma unroll
    for (int r = 0; r < 9; r++) {
        const int ic = r / 3, ti = r % 3;                 // static
        const int srow = h - 1 + ti;
        const bool rok = (unsigned)srow < 256u;
        const float* xrow = x + ((b * 3 + ic) << 16) + (srow << 8);
        {
            const int c = tid;
            float v = (rok && (unsigned)(c - 1) < 256u) ? xrow[c - 1] : 0.f;
            xs[r * 264 + c] = f2h(v);
        }
        if (tid < 2) {
            const int c = tid + 256;
            float v = (rok && (unsigned)(c - 1) < 256u) ? xrow[c - 1] : 0.f;
            xs[r * 264 + c] = f2h(v);
        }
    }
    xs[9 * 264 + tid] = 0;
    if (tid < 8) xs[9 * 264 + 256 + tid] = 0;
    __syncthreads();

    int off[8];
#pragma unroll
    for (int j = 0; j < 8; j++) {
        const int k = quad * 8 + j;
        const int row = (k < 27) ? (k / 3) : 9;
        const int tj  = (k < 27) ? (k - row * 3) : 0;
        off[j] = row * 264 + tj;
    }

    half8 bw[4];
#pragma unroll
    for (int nt = 0; nt < 4; nt++)
        bw[nt] = *(const half8*)(wt1f + nt * 512 + lane * 8);
    float bias[4];
#pragma unroll
    for (int nt = 0; nt < 4; nt++) bias[nt] = cb[nt * 16 + lm];

    unsigned short* fpx = featp + ((((size_t)b << 16) + (h << 8)) << 6);  // +px*64+oc

#pragma unroll
    for (int mt = 0; mt < 4; mt++) {
        const int px = wave * 64 + mt * 16 + lm;
        union { half8 v; unsigned u[4]; } af;
#pragma unroll
        for (int jj = 0; jj < 4; jj++) {
            unsigned lo = xs[off[2 * jj]     + px];
            unsigned hi = xs[off[2 * jj + 1] + px];
            af.u[jj] = lo | (hi << 16);
        }
        float4v d[4];
#pragma unroll
        for (int nt = 0; nt < 4; nt++)
            d[nt] = __builtin_amdgcn_mfma_f32_16x16x32_f16(af.v, bw[nt], (float4v)0.f, 0, 0, 0);

        const int pxs = wave * 64 + mt * 16 + quad * 4;
#pragma unroll
        for (int r = 0; r < 4; r++) {
            unsigned short* sp = fpx + (size_t)(pxs + r) * 64 + lm;
#pragma unroll
            for (int nt = 0; nt < 4; nt++)
                sp[nt * 16] = f2h(d[nt][r] + bias[nt]);
        }
    }
}

// ---------------------------------------------------------------------------
// FUSED conv2 + deform — single-barrier version. 512 threads = 8 waves
// (R13 wave-split mapping). Full 6-row window (ho-2..ho+3) staged up front
// (ring 99KB, slot = row-(ho-2), same XOR swizzle); ONE barrier publishes
// ring + offsets. Then all 18 offsets are read at once, all 9 taps' coords /
// addresses / weights precomputed into static-indexed register arrays, and
// the 9-tap loop is pure {ds_read x8 -> packed-fp16 combine -> 8 MFMA} with
// no per-tap LDS-offset or coords chain. Global-gather fallback recomputes
// from packed clamped coords (rare).
// ---------------------------------------------------------------------------
__global__ __launch_bounds__(512) void fused_kernel(const unsigned short* __restrict__ featp,
                                                    const unsigned short* __restrict__ wt2f,
                                                    const float* __restrict__ ob,
                                                    const unsigned short* __restrict__ wtf,
                                                    const float* __restrict__ db,
                                                    float* __restrict__ out) {
    __shared__ __align__(16) unsigned char ring[6 * 132 * 128];   // 101376 B
    __shared__ float offl[4][18 * 33];                            // 9504 B

    const int tid  = threadIdx.x;
    const int lane = tid & 63;
    const int wv   = tid >> 6;          // 0..7
    const int ow   = wv >> 1;           // old wave 0..3
    const int mtb  = wv & 1;            // old mt 0..1
    const int lm   = lane & 15;
    const int quad = lane >> 4;

    const int bx = blockIdx.x;
    const int strip = ((bx & 7) << 8) | (bx >> 3);
    const int wo_base = (strip & 1) << 7;
    const int ho = (strip >> 1) & 255;
    const int b  = strip >> 9;

    const unsigned* fpq = (const unsigned*)featp + ((size_t)b << 21) + quad * 4;
    const int colb = wo_base + ow * 32 + mtb * 16 + lm;
    float* offw = &offl[ow][0];

    const char* gbase = (const char*)featp + (((size_t)b << 16) << 7);  // batch byte base

// Stage feature row R (if valid) into ring slot SLOT, swizzled.
#define STAGE_ROW(R, SLOT)                                                       \
    {                                                                            \
        const int rr = (R);                                                      \
        if ((unsigned)rr < 256u) {                                               \
            const char* gsrc = gbase + ((size_t)(rr << 8) << 7);                 \
            const unsigned base = (unsigned)((SLOT) * 16896);                    \
            for (int c = tid; c < 1056; c += 512) {                              \
                const int xsl = c >> 3;                                          \
                const int col = wo_base - 2 + xsl;                               \
                if ((unsigned)col < 256u) {                                      \
                    uint4v v = *(const uint4v*)(gsrc + (((size_t)col) << 7)      \
                                                + ((c & 7) << 4));               \
                    const unsigned by = base + (unsigned)(c << 4);               \
                    *(uint4v*)(ring + (by ^ ((unsigned)((xsl & 7) << 4)))) = v;  \
                }                                                                \
            }                                                                    \
        }                                                                        \
    }

    // ---- stage the full 6-row window; completes under phase-1 compute ----
    STAGE_ROW(ho - 2, 0);
    STAGE_ROW(ho - 1, 1);
    STAGE_ROW(ho,     2);
    STAGE_ROW(ho + 1, 3);
    STAGE_ROW(ho + 2, 4);
    STAGE_ROW(ho + 3, 5);

    // ================= PHASE 1: offset conv (EXACT R13 body) =================
    {
        float4v acc1[2];
        acc1[0] = (float4v)0.f; acc1[1] = (float4v)0.f;

        uint4v A[2];

#define C2LOAD(KY, KX, DST)                                                      \
    {                                                                            \
        const int row = ho - 1 + (KY);                                           \
        const bool rok = (unsigned)row < 256u;                                   \
        const int col = colb + (KX) - 1;                                         \
        DST[0] = (uint4v)0;                                                      \
        DST[1] = (uint4v)0;                                                      \
        if (rok && (unsigned)col < 256u) {                                       \
            const unsigned* p = fpq + (((row << 8) + col) << 5);                 \
            DST[0] = *(const uint4v*)p;                                          \
            DST[1] = *(const uint4v*)(p + 16);                                   \
        }                                                                        \
    }

        C2LOAD(0, 0, A);

#pragma unroll
        for (int tap = 0; tap < 9; tap++) {
            half8 bfr[2][2];
            const unsigned short* wp = wt2f + (size_t)(tap * 2) * 1024 + lane * 8;
#pragma unroll
            for (int st = 0; st < 2; st++) {
                bfr[st][0] = *(const half8*)(wp + st * 1024);
                bfr[st][1] = *(const half8*)(wp + st * 1024 + 512);
            }
            uint4v N[2];
            if (tap < 8) {
                const int tn  = tap + 1;
                const int tky = tn / 3;
                const int tkx = tn - 3 * tky;
                C2LOAD(tky, tkx, N);
            }
            {
                union { half8 v; uint4v u; } f0, f1;
                f0.u = A[0]; f1.u = A[1];
                acc1[0] = __builtin_amdgcn_mfma_f32_16x16x32_f16(f0.v, bfr[0][0], acc1[0], 0, 0, 0);
                acc1[1] = __builtin_amdgcn_mfma_f32_16x16x32_f16(f0.v, bfr[0][1], acc1[1], 0, 0, 0);
                acc1[0] = __builtin_amdgcn_mfma_f32_16x16x32_f16(f1.v, bfr[1][0], acc1[0], 0, 0, 0);
                acc1[1] = __builtin_amdgcn_mfma_f32_16x16x32_f16(f1.v, bfr[1][1], acc1[1], 0, 0, 0);
            }
            if (tap < 8) { A[0] = N[0]; A[1] = N[1]; }
        }
#undef C2LOAD

#pragma unroll
        for (int nt = 0; nt < 2; nt++) {
            int oc = nt * 16 + lm;
            if (oc < 18) {
                float bv = ob[oc];
#pragma unroll
                for (int r = 0; r < 4; r++)
                    offw[oc * 33 + mtb * 16 + quad * 4 + r] = acc1[nt][r] + bv;
            }
        }
    }

    __syncthreads();   // ring (6 rows) + all offsets published — ONLY barrier

    // ================= PHASE 2: deform conv =================================
    const int wo0 = wo_base + ow * 32 + mtb * 16 + lm;

    float4v acc[4];
#pragma unroll
    for (int nt = 0; nt < 4; nt++) acc[nt] = (float4v)0.f;

    union AFU { half8 v; unsigned u[4]; };

    // ---- hoisted: all 18 offset reads ----
    float oyv[9], oxv[9];
#pragma unroll
    for (int t = 0; t < 9; t++) {
        oyv[t] = offw[(2 * t) * 33 + mtb * 16 + lm];
        oxv[t] = offw[(2 * t + 1) * 33 + mtb * 16 + lm];
    }

    // ---- hoisted: all coords / addresses / weights (static arrays) ----
    unsigned A00[9], A01[9], A10[9], A11[9];   // un-XORed ring byte addrs
    unsigned M0[9], M1[9];                     // swizzle masks
    unsigned PK[9];                            // packed yb0|yb1|xb0|xb1 (fallback)
    __half2 Wt[9][4];
    unsigned vote = 0;
#pragma unroll
    for (int t = 0; t < 9; t++) {
        const int ky = t / 3, kx = t - 3 * ky;
        float sy = (float)(ho - 1 + ky) + oyv[t];
        float sx = (float)(wo0 - 1 + kx) + oxv[t];
        float y0f = floorf(sy), x0f = floorf(sx);
        float dy = sy - y0f, dx = sx - x0f;
        int y0 = (int)y0f, x0 = (int)x0f;
        float wy0 = ((unsigned)y0 < 256u) ? (1.f - dy) : 0.f;
        float wy1 = ((unsigned)(y0 + 1) < 256u) ? dy : 0.f;
        float wx0 = ((unsigned)x0 < 256u) ? (1.f - dx) : 0.f;
        float wx1 = ((unsigned)(x0 + 1) < 256u) ? dx : 0.f;
        int yb0 = y0 < 0 ? 0 : (y0 > 255 ? 255 : y0);
        int yb1 = (y0 + 1) < 0 ? 0 : ((y0 + 1) > 255 ? 255 : (y0 + 1));
        int xb0 = x0 < 0 ? 0 : (x0 > 255 ? 255 : x0);
        int xb1 = (x0 + 1) < 0 ? 0 : ((x0 + 1) > 255 ? 255 : (x0 + 1));
        Wt[t][0] = __float2half2_rn(wy0 * wx0);
        Wt[t][1] = __float2half2_rn(wy0 * wx1);
        Wt[t][2] = __float2half2_rn(wy1 * wx0);
        Wt[t][3] = __float2half2_rn(wy1 * wx1);
        PK[t] = (unsigned)yb0 | ((unsigned)yb1 << 8)
              | ((unsigned)xb0 << 16) | ((unsigned)xb1 << 24);
        bool inw = (yb0 >= ho - 2) && (yb1 <= ho + 3) &&
                   (xb0 >= wo_base - 2) && (xb1 <= wo_base + 129);
        if (__all(inw)) vote |= (1u << t);
        const int ys0 = yb0 - (ho - 2), ys1 = yb1 - (ho - 2);
        const int xs0 = xb0 - wo_base + 2, xs1 = xb1 - wo_base + 2;
        M0[t] = (unsigned)((xs0 & 7) << 4);
        M1[t] = (unsigned)((xs1 & 7) << 4);
        A00[t] = (unsigned)(ys0 * 16896 + xs0 * 128 + quad * 16);
        A01[t] = (unsigned)(ys0 * 16896 + xs1 * 128 + quad * 16);
        A10[t] = (unsigned)(ys1 * 16896 + xs0 * 128 + quad * 16);
        A11[t] = (unsigned)(ys1 * 16896 + xs1 * 128 + quad * 16);
    }

    // ---- 9 taps: pure gather -> combine -> MFMA ----
#pragma unroll
    for (int t = 0; t < 9; ++t) {
        half8 bfr[2][4];
        {
            const unsigned short* wp = wtf + (size_t)t * 4096 + lane * 8;
#pragma unroll
            for (int nt = 0; nt < 4; nt++) {
                bfr[0][nt] = *(const half8*)(wp + (nt << 9));
                bfr[1][nt] = *(const half8*)(wp + 2048 + (nt << 9));
            }
        }
        uint4v Gg[4][2];
        if (vote & (1u << t)) {
            Gg[0][0] = *(const uint4v*)(ring + (A00[t] ^ M0[t]));
            Gg[0][1] = *(const uint4v*)(ring + ((A00[t] + 64) ^ M0[t]));
            Gg[1][0] = *(const uint4v*)(ring + (A01[t] ^ M1[t]));
            Gg[1][1] = *(const uint4v*)(ring + ((A01[t] + 64) ^ M1[t]));
            Gg[2][0] = *(const uint4v*)(ring + (A10[t] ^ M0[t]));
            Gg[2][1] = *(const uint4v*)(ring + ((A10[t] + 64) ^ M0[t]));
            Gg[3][0] = *(const uint4v*)(ring + (A11[t] ^ M1[t]));
            Gg[3][1] = *(const uint4v*)(ring + ((A11[t] + 64) ^ M1[t]));
        } else {
            const unsigned yb0 = PK[t] & 255u, yb1 = (PK[t] >> 8) & 255u;
            const unsigned xb0 = (PK[t] >> 16) & 255u, xb1 = PK[t] >> 24;
            const unsigned e00 = ((yb0 << 8) + xb0) << 5;
            const unsigned e01 = ((yb0 << 8) + xb1) << 5;
            const unsigned e10 = ((yb1 << 8) + xb0) << 5;
            const unsigned e11 = ((yb1 << 8) + xb1) << 5;
            Gg[0][0] = *(const uint4v*)(fpq + e00);
            Gg[0][1] = *(const uint4v*)(fpq + e00 + 16);
            Gg[1][0] = *(const uint4v*)(fpq + e01);
            Gg[1][1] = *(const uint4v*)(fpq + e01 + 16);
            Gg[2][0] = *(const uint4v*)(fpq + e10);
            Gg[2][1] = *(const uint4v*)(fpq + e10 + 16);
            Gg[3][0] = *(const uint4v*)(fpq + e11);
            Gg[3][1] = *(const uint4v*)(fpq + e11 + 16);
        }
        AFU af[2];
#pragma unroll
        for (int st = 0; st < 2; st++) {
#pragma unroll
            for (int j = 0; j < 4; j++) {
                __half2 s = __hmul2(Wt[t][0], u2h2(Gg[0][st][j]));
                s = __hfma2(Wt[t][1], u2h2(Gg[1][st][j]), s);
                s = __hfma2(Wt[t][2], u2h2(Gg[2][st][j]), s);
                s = __hfma2(Wt[t][3], u2h2(Gg[3][st][j]), s);
                af[st].u[j] = h22u(s);
            }
        }
#pragma unroll
        for (int nt = 0; nt < 4; nt++)
            acc[nt] = __builtin_amdgcn_mfma_f32_16x16x32_f16(
                af[0].v, bfr[0][nt], acc[nt], 0, 0, 0);
#pragma unroll
        for (int nt = 0; nt < 4; nt++)
            acc[nt] = __builtin_amdgcn_mfma_f32_16x16x32_f16(
                af[1].v, bfr[1][nt], acc[nt], 0, 0, 0);
    }

#pragma unroll
    for (int nt = 0; nt < 4; nt++) {
        int oc = nt * 16 + lm;
        float bv = db[oc];
        float* op = out + (((size_t)(b * 64 + oc)) << 16) + (ho << 8)
                  + wo_base + ow * 32 + mtb * 16 + quad * 4;
        float4 v = {acc[nt][0] + bv, acc[nt][1] + bv,
                    acc[nt][2] + bv, acc[nt][3] + bv};
        *(float4*)op = v;
    }
#undef STAGE_ROW
}

// ---------------------------------------------------------------------------
extern "C" void kernel_launch(void* const* d_in, const int* in_sizes, int n_in,
                              void* d_out, int out_size, void* d_ws, size_t ws_size,
                              hipStream_t stream) {
    const float* x  = (const float*)d_in[0];
    const float* cw = (const float*)d_in[1];
    const float* cb = (const float*)d_in[2];
    const float* ow = (const float*)d_in[3];
    const float* ob = (const float*)d_in[4];
    const float* dw = (const float*)d_in[5];
    const float* db = (const float*)d_in[6];
    float* out = (float*)d_out;

    unsigned short* featp = (unsigned short*)d_ws;       // 33.5 MB fp16 NHWC
    float* offsb = (float*)(featp + FEAT_N);             // dead region — reuse
    unsigned short* wt1f = (unsigned short*)offsb;       // 4 KB conv1 B-frags
    unsigned short* wtf  = (unsigned short*)(offsb + OFFS_N);  // 72 KB
    unsigned short* wt2f = wtf + WTF_N;                  // 36 KB

    prep_weights<<<224, 256, 0, stream>>>(dw, ow, cw, wtf, wt2f, wt1f);
    conv1_kernel<<<1024, 256, 0, stream>>>(x, wt1f, cb, featp);
    fused_kernel<<<2048, 512, 0, stream>>>(featp, wt2f, ob, wtf, db, out);
}

// Round 15
// 188.311 us; speedup vs baseline: 1.2607x; 1.2607x over previous
//
#include <hip/hip_runtime.h>
#include <hip/hip_fp16.h>

// Problem constants: B=4, H=W=256, C=64, OC=64, K=3, PAD=1
#define FEAT_N (4*64*256*256)
#define OFFS_N (4*18*256*256)
#define WTF_N  (576*64)            // deform weights, fp16, MFMA-B-fragment order
#define WT2F_N (576*32)            // offset-conv weights, fp16 frags, N padded to 32
#define WT1F_N (4*64*8)            // conv1 weights, fp16 B-frags, K=32 (27 real), N=64

typedef __attribute__((ext_vector_type(8))) _Float16 half8;
typedef __attribute__((ext_vector_type(4))) float float4v;
typedef __attribute__((ext_vector_type(4))) unsigned uint4v;

__device__ __forceinline__ unsigned short f2h(float f) {
    union { __half h; unsigned short u; } c; c.h = __float2half_rn(f); return c.u;
}
__device__ __forceinline__ __half2 u2h2(unsigned u) {
    union { unsigned u; __half2 h; } c; c.u = u; return c.h;
}
__device__ __forceinline__ unsigned h22u(__half2 h) {
    union { __half2 h; unsigned u; } c; c.h = h; return c.u;
}

// ---------------------------------------------------------------------------
// Weight prep (EXACT R13): wtf, wt2f (oc>=18 zero), wt1f. All fp16.
// ---------------------------------------------------------------------------
__global__ __launch_bounds__(256) void prep_weights(const float* __restrict__ dw,
                                                    const float* __restrict__ ow,
                                                    const float* __restrict__ cw,
                                                    unsigned short* __restrict__ wtf,
                                                    unsigned short* __restrict__ wt2f,
                                                    unsigned short* __restrict__ wt1f) {
    int idx = blockIdx.x * 256 + threadIdx.x;
    if (idx < WTF_N) {
        int j    = idx & 7;
        int lane = (idx >> 3) & 63;
        int nt   = (idx >> 9) & 3;
        int ks   = idx >> 11;
        int k    = ks * 32 + ((lane >> 4) << 3) + j;
        int tap  = k >> 6;
        int ic   = k & 63;
        int n    = nt * 16 + (lane & 15);
        wtf[idx] = f2h(dw[n * 576 + ic * 9 + tap]);
    }
    int i2 = idx - WTF_N;
    if (i2 >= 0 && i2 < WT2F_N) {
        int j    = i2 & 7;
        int lane = (i2 >> 3) & 63;
        int nt   = (i2 >> 9) & 1;
        int ks   = i2 >> 10;
        int k    = ks * 32 + ((lane >> 4) << 3) + j;
        int tap  = k >> 6;
        int ic   = k & 63;
        int n    = nt * 16 + (lane & 15);
        wt2f[i2] = (n < 18) ? f2h(ow[n * 576 + ic * 9 + tap]) : (unsigned short)0;
    }
    int i3 = idx - WTF_N - WT2F_N;
    if (i3 >= 0 && i3 < WT1F_N) {
        int j    = i3 & 7;
        int lane = (i3 >> 3) & 63;
        int nt   = (i3 >> 9) & 3;
        int n    = nt * 16 + (lane & 15);
        int k    = ((lane >> 4) << 3) + j;
        wt1f[i3] = (k < 27) ? f2h(cw[n * 27 + k]) : (unsigned short)0;
    }
}

// ---------------------------------------------------------------------------
// conv1 (EXACT R13): MFMA im2col GEMM, M=256 px, N=64 oc, K=32, fp16.
// ---------------------------------------------------------------------------
__global__ __launch_bounds__(256) void conv1_kernel(const float* __restrict__ x,
                                                    const unsigned short* __restrict__ wt1f,
                                                    const float* __restrict__ cb,
                                                    unsigned short* __restrict__ featp) {
    __shared__ unsigned short xs[10 * 264];   // rows 0..8 = (ic*3+ti), row 9 = zeros
    const int tid  = threadIdx.x;
    const int lane = tid & 63;
    const int wave = tid >> 6;
    const int lm   = lane & 15;
    const int quad = lane >> 4;

    const int bx = blockIdx.x;
    const int b  = bx >> 8;
    const int h  = bx & 255;

#pragma unroll
    for (int r = 0; r < 9; r++) {
        const int ic = r / 3, ti = r % 3;                 // static
        const int srow = h - 1 + ti;
        const bool rok = (unsigned)srow < 256u;
        const float* xrow = x + ((b * 3 + ic) << 16) + (srow << 8);
        {
            const int c = tid;
            float v = (rok && (unsigned)(c - 1) < 256u) ? xrow[c - 1] : 0.f;
            xs[r * 264 + c] = f2h(v);
        }
        if (tid < 2) {
            const int c = tid + 256;
            float v = (rok && (unsigned)(c - 1) < 256u) ? xrow[c - 1] : 0.f;
            xs[r * 264 + c] = f2h(v);
        }
    }
    xs[9 * 264 + tid] = 0;
    if (tid < 8) xs[9 * 264 + 256 + tid] = 0;
    __syncthreads();

    int off[8];
#pragma unroll
    for (int j = 0; j < 8; j++) {
        const int k = quad * 8 + j;
        const int row = (k < 27) ? (k / 3) : 9;
        const int tj  = (k < 27) ? (k - row * 3) : 0;
        off[j] = row * 264 + tj;
    }

    half8 bw[4];
#pragma unroll
    for (int nt = 0; nt < 4; nt++)
        bw[nt] = *(const half8*)(wt1f + nt * 512 + lane * 8);
    float bias[4];
#pragma unroll
    for (int nt = 0; nt < 4; nt++) bias[nt] = cb[nt * 16 + lm];

    unsigned short* fpx = featp + ((((size_t)b << 16) + (h << 8)) << 6);  // +px*64+oc

#pragma unroll
    for (int mt = 0; mt < 4; mt++) {
        const int px = wave * 64 + mt * 16 + lm;
        union { half8 v; unsigned u[4]; } af;
#pragma unroll
        for (int jj = 0; jj < 4; jj++) {
            unsigned lo = xs[off[2 * jj]     + px];
            unsigned hi = xs[off[2 * jj + 1] + px];
            af.u[jj] = lo | (hi << 16);
        }
        float4v d[4];
#pragma unroll
        for (int nt = 0; nt < 4; nt++)
            d[nt] = __builtin_amdgcn_mfma_f32_16x16x32_f16(af.v, bw[nt], (float4v)0.f, 0, 0, 0);

        const int pxs = wave * 64 + mt * 16 + quad * 4;
#pragma unroll
        for (int r = 0; r < 4; r++) {
            unsigned short* sp = fpx + (size_t)(pxs + r) * 64 + lm;
#pragma unroll
            for (int nt = 0; nt < 4; nt++)
                sp[nt * 16] = f2h(d[nt][r] + bias[nt]);
        }
    }
}

// ---------------------------------------------------------------------------
// FUSED conv2 + deform — R13 structure with ONE change: the initial 4-row
// ring window is published (barrier) BEFORE phase 1, and phase 1's
// A-fragment loads read from the ring (bit-identical bytes, same XOR
// addressing as phase 2's LDS path, per-lane zero-guard for conv borders)
// instead of global featp. The old post-phase-1 barrier is dropped (offl is
// same-wave write->read; ring is not rewritten until tap-3's barrier pair).
// Everything else byte-identical to R13 (best verified: fused 120.4 us).
// ---------------------------------------------------------------------------
__global__ __launch_bounds__(512, 4) void fused_kernel(const unsigned short* __restrict__ featp,
                                                       const unsigned short* __restrict__ wt2f,
                                                       const float* __restrict__ ob,
                                                       const unsigned short* __restrict__ wtf,
                                                       const float* __restrict__ db,
                                                       float* __restrict__ out) {
    __shared__ __align__(16) unsigned char ring[4 * 132 * 128];   // 67584 B
    __shared__ float offl[4][18 * 33];                            // 9504 B

    const int tid  = threadIdx.x;
    const int lane = tid & 63;
    const int wv   = tid >> 6;          // 0..7
    const int ow   = wv >> 1;           // old wave 0..3
    const int mtb  = wv & 1;            // old mt 0..1
    const int lm   = lane & 15;
    const int quad = lane >> 4;

    const int bx = blockIdx.x;
    const int strip = ((bx & 7) << 8) | (bx >> 3);
    const int wo_base = (strip & 1) << 7;
    const int ho = (strip >> 1) & 255;
    const int b  = strip >> 9;

    const unsigned* fpq = (const unsigned*)featp + ((size_t)b << 21) + quad * 4;
    const int colb = wo_base + ow * 32 + mtb * 16 + lm;
    float* offw = &offl[ow][0];

    const char* gbase = (const char*)featp + (((size_t)b << 16) << 7);  // batch byte base

// Stage feature row R (if valid) into ring slot R&3, swizzled (EXACT R13).
#define STAGE_ROW(R)                                                             \
    {                                                                            \
        const int rr = (R);                                                      \
        if ((unsigned)rr < 256u) {                                               \
            const char* gsrc = gbase + ((size_t)(rr << 8) << 7);                 \
            const unsigned base = (unsigned)((rr & 3) * 16896);                  \
            for (int c = tid; c < 1056; c += 512) {                              \
                const int xsl = c >> 3;                                          \
                const int col = wo_base - 2 + xsl;                               \
                if ((unsigned)col < 256u) {                                      \
                    uint4v v = *(const uint4v*)(gsrc + (((size_t)col) << 7)      \
                                                + ((c & 7) << 4));               \
                    const unsigned by = base + (unsigned)(c << 4);               \
                    *(uint4v*)(ring + (by ^ ((unsigned)((xsl & 7) << 4)))) = v;  \
                }                                                                \
            }                                                                    \
        }                                                                        \
    }

    STAGE_ROW(ho - 2);
    STAGE_ROW(ho - 1);
    STAGE_ROW(ho);
    STAGE_ROW(ho + 1);

    __syncthreads();   // ring rows ho-2..ho+1 published BEFORE phase 1

    // ================= PHASE 1: offset conv (A-frags from ring) =============
    {
        float4v acc1[2];
        acc1[0] = (float4v)0.f; acc1[1] = (float4v)0.f;

        uint4v A[2];

// Phase-1 load from ring: rows ho-1..ho+1 and cols [wo_base-1, wo_base+128]
// are inside the staged window; zero-guard keeps conv border semantics.
#define C2LOAD(KY, KX, DST)                                                      \
    {                                                                            \
        const int row = ho - 1 + (KY);                                           \
        const bool rok = (unsigned)row < 256u;                                   \
        const int col = colb + (KX) - 1;                                         \
        DST[0] = (uint4v)0;                                                      \
        DST[1] = (uint4v)0;                                                      \
        if (rok && (unsigned)col < 256u) {                                       \
            const int xs = col - wo_base + 2;                                    \
            const unsigned m = (unsigned)((xs & 7) << 4);                        \
            const unsigned a = (unsigned)((row & 3) * 16896 + xs * 128           \
                                          + quad * 16);                          \
            DST[0] = *(const uint4v*)(ring + (a ^ m));                           \
            DST[1] = *(const uint4v*)(ring + ((a + 64) ^ m));                    \
        }                                                                        \
    }

        C2LOAD(0, 0, A);

#pragma unroll
        for (int tap = 0; tap < 9; tap++) {
            half8 bfr[2][2];
            const unsigned short* wp = wt2f + (size_t)(tap * 2) * 1024 + lane * 8;
#pragma unroll
            for (int st = 0; st < 2; st++) {
                bfr[st][0] = *(const half8*)(wp + st * 1024);
                bfr[st][1] = *(const half8*)(wp + st * 1024 + 512);
            }
            uint4v N[2];
            if (tap < 8) {
                const int tn  = tap + 1;
                const int tky = tn / 3;
                const int tkx = tn - 3 * tky;
                C2LOAD(tky, tkx, N);
            }
            {
                union { half8 v; uint4v u; } f0, f1;
                f0.u = A[0]; f1.u = A[1];
                acc1[0] = __builtin_amdgcn_mfma_f32_16x16x32_f16(f0.v, bfr[0][0], acc1[0], 0, 0, 0);
                acc1[1] = __builtin_amdgcn_mfma_f32_16x16x32_f16(f0.v, bfr[0][1], acc1[1], 0, 0, 0);
                acc1[0] = __builtin_amdgcn_mfma_f32_16x16x32_f16(f1.v, bfr[1][0], acc1[0], 0, 0, 0);
                acc1[1] = __builtin_amdgcn_mfma_f32_16x16x32_f16(f1.v, bfr[1][1], acc1[1], 0, 0, 0);
            }
            if (tap < 8) { A[0] = N[0]; A[1] = N[1]; }
        }
#undef C2LOAD

        // Store offsets to per-(old-wave) LDS; this wave covers pxw slice
        // [mtb*16, mtb*16+16) and reads back ONLY its own slice (no barrier
        // needed — same-wave LDS ordering via lgkmcnt).
#pragma unroll
        for (int nt = 0; nt < 2; nt++) {
            int oc = nt * 16 + lm;
            if (oc < 18) {
                float bv = ob[oc];
#pragma unroll
                for (int r = 0; r < 4; r++)
                    offw[oc * 33 + mtb * 16 + quad * 4 + r] = acc1[nt][r] + bv;
            }
        }
    }

    // ================= PHASE 2: deform conv (LDS-window gathers) ============
    const int wo0 = wo_base + ow * 32 + mtb * 16 + lm;

    float4v acc[4];
#pragma unroll
    for (int nt = 0; nt < 4; nt++) acc[nt] = (float4v)0.f;

    union AFU { half8 v; unsigned u[4]; };

// One tap (EXACT R13 DOTAP body).
#define DOTAP(KY, KX, OY, OX)                                                    \
    {                                                                            \
        float sy = (float)(ho - 1 + (KY)) + (OY);                                \
        float sx = (float)(wo0 - 1 + (KX)) + (OX);                               \
        float y0f = floorf(sy), x0f = floorf(sx);                                \
        float dy = sy - y0f, dx = sx - x0f;                                      \
        int y0 = (int)y0f, x0 = (int)x0f;                                        \
        float wy0 = ((unsigned)y0 < 256u) ? (1.f - dy) : 0.f;                    \
        float wy1 = ((unsigned)(y0 + 1) < 256u) ? dy : 0.f;                      \
        float wx0 = ((unsigned)x0 < 256u) ? (1.f - dx) : 0.f;                    \
        float wx1 = ((unsigned)(x0 + 1) < 256u) ? dx : 0.f;                      \
        int yb0 = y0 < 0 ? 0 : (y0 > 255 ? 255 : y0);                            \
        int yb1 = (y0 + 1) < 0 ? 0 : ((y0 + 1) > 255 ? 255 : (y0 + 1));          \
        int xb0 = x0 < 0 ? 0 : (x0 > 255 ? 255 : x0);                            \
        int xb1 = (x0 + 1) < 0 ? 0 : ((x0 + 1) > 255 ? 255 : (x0 + 1));          \
        __half2 W0 = __float2half2_rn(wy0 * wx0);                                \
        __half2 W1 = __float2half2_rn(wy0 * wx1);                                \
        __half2 W2 = __float2half2_rn(wy1 * wx0);                                \
        __half2 W3 = __float2half2_rn(wy1 * wx1);                                \
        uint4v Gg[4][2];                                                         \
        bool inw = (yb0 >= ho - 2 + (KY)) && (yb1 <= ho + (KY) + 1) &&           \
                   (xb0 >= wo_base - 2) && (xb1 <= wo_base + 129);               \
        if (__all(inw)) {                                                        \
            const int xs0 = xb0 - wo_base + 2, xs1 = xb1 - wo_base + 2;          \
            const unsigned m0 = (unsigned)((xs0 & 7) << 4);                      \
            const unsigned m1 = (unsigned)((xs1 & 7) << 4);                      \
            const unsigned r0b = (unsigned)((yb0 & 3) * 16896 + quad * 16);      \
            const unsigned r1b = (unsigned)((yb1 & 3) * 16896 + quad * 16);      \
            const unsigned a00 = r0b + (unsigned)(xs0 << 7);                     \
            const unsigned a01 = r0b + (unsigned)(xs1 << 7);                     \
            const unsigned a10 = r1b + (unsigned)(xs0 << 7);                     \
            const unsigned a11 = r1b + (unsigned)(xs1 << 7);                     \
            Gg[0][0] = *(const uint4v*)(ring + (a00 ^ m0));                      \
            Gg[0][1] = *(const uint4v*)(ring + ((a00 + 64) ^ m0));               \
            Gg[1][0] = *(const uint4v*)(ring + (a01 ^ m1));                      \
            Gg[1][1] = *(const uint4v*)(ring + ((a01 + 64) ^ m1));               \
            Gg[2][0] = *(const uint4v*)(ring + (a10 ^ m0));                      \
            Gg[2][1] = *(const uint4v*)(ring + ((a10 + 64) ^ m0));               \
            Gg[3][0] = *(const uint4v*)(ring + (a11 ^ m1));                      \
            Gg[3][1] = *(const uint4v*)(ring + ((a11 + 64) ^ m1));               \
        } else {                                                                 \
            const unsigned e00 = ((yb0 << 8) + xb0) << 5;                        \
            const unsigned e01 = ((yb0 << 8) + xb1) << 5;                        \
            const unsigned e10 = ((yb1 << 8) + xb0) << 5;                        \
            const unsigned e11 = ((yb1 << 8) + xb1) << 5;                        \
            Gg[0][0] = *(const uint4v*)(fpq + e00);                              \
            Gg[0][1] = *(const uint4v*)(fpq + e00 + 16);                         \
            Gg[1][0] = *(const uint4v*)(fpq + e01);                              \
            Gg[1][1] = *(const uint4v*)(fpq + e01 + 16);                         \
            Gg[2][0] = *(const uint4v*)(fpq + e10);                              \
            Gg[2][1] = *(const uint4v*)(fpq + e10 + 16);                         \
            Gg[3][0] = *(const uint4v*)(fpq + e11);                              \
            Gg[3][1] = *(const uint4v*)(fpq + e11 + 16);                         \
        }                                                                        \
        AFU af[2];                                                               \
        _Pragma("unroll")                                                        \
        for (int st = 0; st < 2; st++) {                                         \
            _Pragma("unroll")                                                    \
            for (int j = 0; j < 4; j++) {                                        \
                __half2 s = __hmul2(W0, u2h2(Gg[0][st][j]));                     \
                s = __hfma2(W1, u2h2(Gg[1][st][j]), s);                          \
                s = __hfma2(W2, u2h2(Gg[2][st][j]), s);                          \
                s = __hfma2(W3, u2h2(Gg[3][st][j]), s);                          \
                af[st].u[j] = h22u(s);                                           \
            }                                                                    \
        }                                                                        \
        _Pragma("unroll")                                                        \
        for (int nt = 0; nt < 4; nt++)                                           \
            acc[nt] = __builtin_amdgcn_mfma_f32_16x16x32_f16(                    \
                af[0].v, bfr[0][nt], acc[nt], 0, 0, 0);                          \
        _Pragma("unroll")                                                        \
        for (int nt = 0; nt < 4; nt++)                                           \
            acc[nt] = __builtin_amdgcn_mfma_f32_16x16x32_f16(                    \
                af[1].v, bfr[1][nt], acc[nt], 0, 0, 0);                          \
    }

#pragma unroll
    for (int tap = 0; tap < 9; ++tap) {
        const int ky = tap / 3;
        const int kx = tap - 3 * ky;
        if (tap == 3) { __syncthreads(); STAGE_ROW(ho + 2); __syncthreads(); }
        if (tap == 6) { __syncthreads(); STAGE_ROW(ho + 3); __syncthreads(); }

        float oy = offw[(2 * tap) * 33 + mtb * 16 + lm];
        float ox = offw[(2 * tap + 1) * 33 + mtb * 16 + lm];

        half8 bfr[2][4];                                // B-frags, both steps
        {
            const unsigned short* wp = wtf + (size_t)tap * 4096 + lane * 8;
#pragma unroll
            for (int nt = 0; nt < 4; nt++) {
                bfr[0][nt] = *(const half8*)(wp + (nt << 9));
                bfr[1][nt] = *(const half8*)(wp + 2048 + (nt << 9));
            }
        }

        DOTAP(ky, kx, oy, ox);
    }

#pragma unroll
    for (int nt = 0; nt < 4; nt++) {
        int oc = nt * 16 + lm;
        float bv = db[oc];
        float* op = out + (((size_t)(b * 64 + oc)) << 16) + (ho << 8)
                  + wo_base + ow * 32 + mtb * 16 + quad * 4;
        float4 v = {acc[nt][0] + bv, acc[nt][1] + bv,
                    acc[nt][2] + bv, acc[nt][3] + bv};
        *(float4*)op = v;
    }
#undef DOTAP
#undef STAGE_ROW
}

// ---------------------------------------------------------------------------
extern "C" void kernel_launch(void* const* d_in, const int* in_sizes, int n_in,
                              void* d_out, int out_size, void* d_ws, size_t ws_size,
                              hipStream_t stream) {
    const float* x  = (const float*)d_in[0];
    const float* cw = (const float*)d_in[1];
    const float* cb = (const float*)d_in[2];
    const float* ow = (const float*)d_in[3];
    const float* ob = (const float*)d_in[4];
    const float* dw = (const float*)d_in[5];
    const float* db = (const float*)d_in[6];
    float* out = (float*)d_out;

    unsigned short* featp = (unsigned short*)d_ws;       // 33.5 MB fp16 NHWC
    float* offsb = (float*)(featp + FEAT_N);             // dead region — reuse
    unsigned short* wt1f = (unsigned short*)offsb;       // 4 KB conv1 B-frags
    unsigned short* wtf  = (unsigned short*)(offsb + OFFS_N);  // 72 KB
    unsigned short* wt2f = wtf + WTF_N;                  // 36 KB

    prep_weights<<<224, 256, 0, stream>>>(dw, ow, cw, wtf, wt2f, wt1f);
    conv1_kernel<<<1024, 256, 0, stream>>>(x, wt1f, cb, featp);
    fused_kernel<<<2048, 512, 0, stream>>>(featp, wt2f, ob, wtf, db, out);
}